// Round 8
// baseline (790.218 us; speedup 1.0000x reference)
//
#include <hip/hip_runtime.h>
#include <math.h>
#include <stddef.h>

#define BB 32
#define LL 2048
#define DD 1024
#define HH 256
#define NSTEPS 4
#define RD 8192
#define G3 768

#define OUT_REGS 67108864UL
#define OUT_PO   67371008UL
#define OUT_TR   67403776UL

#define MM_KC 128
#define ATS 516  // per-bq stride: 128*4 + 4

__device__ __forceinline__ float sigf(float x){ return 1.0f/(1.0f+expf(-x)); }
__device__ __forceinline__ float geluf(float x){ return x*0.5f*(1.0f+erff(x*0.70710678118654752f)); }

union SMem {
  struct { float At[8*ATS]; float Wt[MM_KC*64]; } mm;                      // 49280 B
  struct { float A[64*68]; float B[64*64]; } w2;
  struct { float hnew[HH]; float logit[40]; float wsm[40]; float dws[32];
           float redS[4]; float redQ[4]; } ctl;
  struct { float p[DD]; } pool;
  struct { float d1[HH]; float redQ[4]; float stats[1]; float dws[32]; } dec;
};

struct MegaP {
  const float *x, *u, *W_e1, *b_e1, *W_e2, *b_e2, *W_ih, *b_ih, *W_hh, *b_hh, *h0;
  const float *W_op, *b_op, *W_src, *b_src, *W_dst, *b_dst, *W_aux, *b_aux;
  const float *W_proj, *op_sc, *Wv, *bv, *Wo, *bo, *W_d1, *b_d1, *W_d2, *b_d2, *norm_w;
  float *pool_part, *pooled, *e1, *regs, *gip_part, *gi_part, *ghpart, *hbuf, *halt;
  float *opw, *live, *srcv, *dstv, *tvec, *avec, *p8a, *p10, *d1part, *pn;
  float *W2, *bvWo;
  float *rlbuf, *dwbuf, *statsb;
  float *out;
};

// rl for one d-quad of batch b, from pv outputs + control scalars (exact combine math)
__device__ __forceinline__ float4 rl_now4(const MegaP& P, int b, int d,
    const float* ow, float live, float mean, float rstd, float osc){
  float4 sv = *(const float4*)(P.srcv + (size_t)b*DD + d);
  float4 dv = *(const float4*)(P.dstv + (size_t)b*DD + d);
  float pmx=0,pmy=0,pmz=0,pmw=0, atx=0,aty=0,atz=0,atw=0;
  #pragma unroll
  for (int l=0;l<8;++l){
    float4 v = *(const float4*)(P.p8a + (size_t)(l*BB+b)*DD + d);
    pmx+=v.x; pmy+=v.y; pmz+=v.z; pmw+=v.w;
    float4 w = *(const float4*)(P.p10 + (size_t)(l*BB+b)*DD + d);
    atx+=w.x; aty+=w.y; atz+=w.z; atw+=w.w;
  }
  float4 bo4 = *(const float4*)(P.bo + d);
  float4 bw4 = *(const float4*)(P.bvWo + d);
  atx += ow[6]*(bo4.x+bw4.x); aty += ow[6]*(bo4.y+bw4.y);
  atz += ow[6]*(bo4.z+bw4.z); atw += ow[6]*(bo4.w+bw4.w);
  float S[4]={sv.x,sv.y,sv.z,sv.w}, Dv[4]={dv.x,dv.y,dv.z,dv.w};
  float PM[4]={pmx,pmy,pmz,pmw}, AT[4]={atx,aty,atz,atw};
  float R[4];
  #pragma unroll
  for (int c=0;c<4;++c){
    float sc=S[c], dc=Dv[c];
    float r = ow[0]*dc + ow[1]*(dc+sc) + ow[2]*(sigf(sc)*dc)
            + ow[3]*((sc-mean)*rstd)
            + PM[c] + ow[5]*(sc+dc) + AT[c]
            - ow[7]*sc + ow[8]*(sc*osc) + ow[9]*sc
            + ow[10]*fmaxf(sc,dc) + ow[11]*fminf(sc,dc)
            + ow[12]*fmaxf(sc,0.0f)
            + ow[13]*tanhf(sc) + ow[15]*dc;
    R[c] = r*live;
  }
  float4 o; o.x=R[0]; o.y=R[1]; o.z=R[2]; o.w=R[3];
  return o;
}

// ---------------- generic tiled partial matmul (plain inputs), nk K-chunks ----------------
__device__ void st_mm2(SMem& sm, const float* __restrict__ in, int in_ld,
                       const float* __restrict__ W, int row_off, int ldw,
                       float* __restrict__ part, int nb, int layer, int nk, int t){
  float acc[16];
  #pragma unroll
  for (int i=0;i<16;++i) acc[i]=0.f;
  const int n0 = nb*64;
  for (int c=0;c<nk;++c){
    const int k0 = (layer*nk + c)*MM_KC;
    __syncthreads();
    if (t < 128){
      #pragma unroll
      for (int rep=0; rep<8; ++rep){
        int idx = t + rep*128;
        int b = idx & 31, k4 = idx >> 5;
        float4 g = *(const float4*)(in + (size_t)b*in_ld + k0 + k4*4);
        float* a = sm.mm.At + (b>>2)*ATS + k4*16 + (b&3);
        a[0]=g.x; a[4]=g.y; a[8]=g.z; a[12]=g.w;
      }
      #pragma unroll
      for (int rep=0; rep<16; ++rep){
        int idx = t + rep*128;
        int k = idx >> 4, nq4 = idx & 15;
        *(float4*)(sm.mm.Wt + k*64 + nq4*4) =
          *(const float4*)(W + (size_t)(row_off + k0 + k)*ldw + n0 + nq4*4);
      }
    }
    __syncthreads();
    if (t < 128){
      const int nq = t & 15, bq = t >> 4;
      const float4* A4 = (const float4*)sm.mm.At + bq*129;
      const float4* W4 = (const float4*)sm.mm.Wt + nq;
      #pragma unroll 4
      for (int kk=0; kk<MM_KC; ++kk){
        float4 a = A4[kk];
        float4 w = W4[kk*16];
        acc[0] +=a.x*w.x; acc[1] +=a.x*w.y; acc[2] +=a.x*w.z; acc[3] +=a.x*w.w;
        acc[4] +=a.y*w.x; acc[5] +=a.y*w.y; acc[6] +=a.y*w.z; acc[7] +=a.y*w.w;
        acc[8] +=a.z*w.x; acc[9] +=a.z*w.y; acc[10]+=a.z*w.z; acc[11]+=a.z*w.w;
        acc[12]+=a.w*w.x; acc[13]+=a.w*w.y; acc[14]+=a.w*w.z; acc[15]+=a.w*w.w;
      }
    }
  }
  if (t < 128){
    const int nq = t & 15, bq = t >> 4;
    float* pp = part + (size_t)(layer*32 + bq*4)*ldw + n0 + nq*4;
    #pragma unroll
    for (int i=0;i<4;++i){
      float4 o; o.x=acc[i*4]; o.y=acc[i*4+1]; o.z=acc[i*4+2]; o.w=acc[i*4+3];
      *(float4*)(pp + (size_t)i*ldw) = o;
    }
  }
}

// ---------------- regs matmul with deferred rank-1 deltas ----------------
// A = regs_base + sum_{s'<s_done} dw[s'] (x) rl[s'];  rl[s_done-1] computed on the fly.
// nk=2 fixed; k-range [layer*256, layer*256+256) => r = layer>>2 constant per block.
__device__ void st_mm_regs(SMem& sm, const MegaP& P, int s_done,
                           const float* __restrict__ W, int row_off, int ldw,
                           float* __restrict__ part, int nb, int layer, int t, bool wr){
  float acc[16];
  #pragma unroll
  for (int i=0;i<16;++i) acc[i]=0.f;
  const int n0 = nb*64;
  const int b = t & 31;
  const int r_blk = layer >> 2;
  float ow[16]; float live=0.f, mean=0.f, rstd=0.f, osc=0.f, dw_now=0.f;
  float dw_prev[3] = {0.f,0.f,0.f};
  if (s_done >= 1 && t < 128){
    #pragma unroll
    for (int i=0;i<16;++i) ow[i] = P.opw[b*16+i];
    live = P.live[b]; mean = P.statsb[b*2]; rstd = P.statsb[b*2+1]; osc = P.op_sc[0];
    dw_now = P.dwbuf[(size_t)(s_done-1)*256 + b*8 + r_blk];
    #pragma unroll
    for (int sp=0; sp<3; ++sp)
      if (sp < s_done-1) dw_prev[sp] = P.dwbuf[(size_t)sp*256 + b*8 + r_blk];
  }
  for (int c=0;c<2;++c){
    const int k0 = (layer*2 + c)*MM_KC;
    __syncthreads();
    if (t < 128){
      #pragma unroll
      for (int rep=0; rep<8; ++rep){
        int idx = t + rep*128;
        int k4 = idx >> 5;
        int kq = k0 + k4*4;
        int dq = kq & (DD-1);
        float4 g = *(const float4*)(P.regs + (size_t)b*RD + kq);
        #pragma unroll
        for (int sp=0; sp<3; ++sp){
          if (sp < s_done-1){
            float4 rv = *(const float4*)(P.rlbuf + ((size_t)sp*BB + b)*DD + dq);
            g.x += dw_prev[sp]*rv.x; g.y += dw_prev[sp]*rv.y;
            g.z += dw_prev[sp]*rv.z; g.w += dw_prev[sp]*rv.w;
          }
        }
        if (s_done >= 1){
          float4 rn = rl_now4(P, b, dq, ow, live, mean, rstd, osc);
          g.x += dw_now*rn.x; g.y += dw_now*rn.y;
          g.z += dw_now*rn.z; g.w += dw_now*rn.w;
          if (wr) *(float4*)(P.rlbuf + ((size_t)(s_done-1)*BB + b)*DD + dq) = rn;
        }
        float* a = sm.mm.At + (b>>2)*ATS + k4*16 + (b&3);
        a[0]=g.x; a[4]=g.y; a[8]=g.z; a[12]=g.w;
      }
      #pragma unroll
      for (int rep=0; rep<16; ++rep){
        int idx = t + rep*128;
        int k = idx >> 4, nq4 = idx & 15;
        *(float4*)(sm.mm.Wt + k*64 + nq4*4) =
          *(const float4*)(W + (size_t)(row_off + k0 + k)*ldw + n0 + nq4*4);
      }
    }
    __syncthreads();
    if (t < 128){
      const int nq = t & 15, bq = t >> 4;
      const float4* A4 = (const float4*)sm.mm.At + bq*129;
      const float4* W4 = (const float4*)sm.mm.Wt + nq;
      #pragma unroll 4
      for (int kk=0; kk<MM_KC; ++kk){
        float4 a = A4[kk];
        float4 w = W4[kk*16];
        acc[0] +=a.x*w.x; acc[1] +=a.x*w.y; acc[2] +=a.x*w.z; acc[3] +=a.x*w.w;
        acc[4] +=a.y*w.x; acc[5] +=a.y*w.y; acc[6] +=a.y*w.z; acc[7] +=a.y*w.w;
        acc[8] +=a.z*w.x; acc[9] +=a.z*w.y; acc[10]+=a.z*w.z; acc[11]+=a.z*w.w;
        acc[12]+=a.w*w.x; acc[13]+=a.w*w.y; acc[14]+=a.w*w.z; acc[15]+=a.w*w.w;
      }
    }
  }
  if (t < 128){
    const int nq = t & 15, bq = t >> 4;
    float* pp = part + (size_t)(layer*32 + bq*4)*ldw + n0 + nq*4;
    #pragma unroll
    for (int i=0;i<4;++i){
      float4 o; o.x=acc[i*4]; o.y=acc[i*4+1]; o.z=acc[i*4+2]; o.w=acc[i*4+3];
      *(float4*)(pp + (size_t)i*ldw) = o;
    }
  }
}

// ---------------- W2 = Wv @ Wo (virtual blocks 0-255) ----------------
__device__ void st_w2(SMem& sm, const MegaP& P, int blk, int t){
  const int r0 = (blk>>4)*64, n0 = (blk&15)*64;
  const int tr = t>>4, tc = t&15;
  float4 acc[4];
  acc[0]=make_float4(0,0,0,0); acc[1]=make_float4(0,0,0,0);
  acc[2]=make_float4(0,0,0,0); acc[3]=make_float4(0,0,0,0);
  for (int kc=0; kc<16; ++kc){
    const int k0 = kc*64;
    __syncthreads();
    #pragma unroll
    for (int rep=0; rep<4; ++rep){
      int idx = t + rep*256;
      int r = idx>>4, c4 = (idx&15)*4;
      *(float4*)(sm.w2.A + r*68 + c4) = *(const float4*)(P.Wv + (size_t)(r0+r)*DD + k0 + c4);
      *(float4*)(sm.w2.B + r*64 + c4) = *(const float4*)(P.Wo + (size_t)(k0+r)*DD + n0 + c4);
    }
    __syncthreads();
    #pragma unroll 4
    for (int k=0;k<64;++k){
      float4 bv4 = *(const float4*)(sm.w2.B + k*64 + tc*4);
      float a0 = sm.w2.A[(tr*4+0)*68 + k];
      float a1 = sm.w2.A[(tr*4+1)*68 + k];
      float a2 = sm.w2.A[(tr*4+2)*68 + k];
      float a3 = sm.w2.A[(tr*4+3)*68 + k];
      acc[0].x += a0*bv4.x; acc[0].y += a0*bv4.y; acc[0].z += a0*bv4.z; acc[0].w += a0*bv4.w;
      acc[1].x += a1*bv4.x; acc[1].y += a1*bv4.y; acc[1].z += a1*bv4.z; acc[1].w += a1*bv4.w;
      acc[2].x += a2*bv4.x; acc[2].y += a2*bv4.y; acc[2].z += a2*bv4.z; acc[2].w += a2*bv4.w;
      acc[3].x += a3*bv4.x; acc[3].y += a3*bv4.y; acc[3].z += a3*bv4.z; acc[3].w += a3*bv4.w;
    }
  }
  #pragma unroll
  for (int i=0;i<4;++i)
    *(float4*)(P.W2 + (size_t)(r0+tr*4+i)*DD + n0 + tc*4) = acc[i];
}

// ---------------- pool partials (no LDS, pure HBM stream) ----------------
__global__ __launch_bounds__(256) void k_pool(MegaP P){
  const int blk = blockIdx.x, t = threadIdx.x;
  const int b = blk >> 5, c = blk & 31;
  const float* xp = P.x + (size_t)b*LL*DD + (size_t)c*64*DD + t*4;
  float ax=0.f, ay=0.f, az=0.f, aw=0.f;
  #pragma unroll 8
  for (int l=0;l<64;++l){
    float4 v = *(const float4*)(xp + (size_t)l*DD);
    ax+=v.x; ay+=v.y; az+=v.z; aw+=v.w;
  }
  float4 o; o.x=ax; o.y=ay; o.z=az; o.w=aw;
  *(float4*)(P.pool_part + (size_t)blk*DD + t*4) = o;
}

// ---------------- S1: pool finalize + h/halt init + e1 ----------------
__global__ __launch_bounds__(256) void k_s1(MegaP P){
  __shared__ SMem sm;
  const int b = blockIdx.x, t = threadIdx.x;
  float ax=0.f, ay=0.f, az=0.f, aw=0.f;
  #pragma unroll 8
  for (int c=0;c<32;++c){
    float4 v = *(const float4*)(P.pool_part + (size_t)(b*32+c)*DD + t*4);
    ax+=v.x; ay+=v.y; az+=v.z; aw+=v.w;
  }
  const float inv = 1.0f/(float)LL;
  float4 o; o.x=ax*inv; o.y=ay*inv; o.z=az*inv; o.w=aw*inv;
  *(float4*)(P.pooled + (size_t)b*DD + t*4) = o;
  *(float4*)(sm.pool.p + t*4) = o;
  P.hbuf[b*HH + t] = P.h0[t];
  if (t==0) P.halt[b] = 0.f;
  __syncthreads();
  float a0=0.f,a1=0.f,a2=0.f,a3=0.f;
  #pragma unroll 2
  for (int k=0;k<DD;k+=4){
    a0 += sm.pool.p[k]  *P.W_e1[(k)*HH + t];
    a1 += sm.pool.p[k+1]*P.W_e1[(k+1)*HH + t];
    a2 += sm.pool.p[k+2]*P.W_e1[(k+2)*HH + t];
    a3 += sm.pool.p[k+3]*P.W_e1[(k+3)*HH + t];
  }
  float a = (a0+a1)+(a2+a3) + P.b_e1[t];
  P.e1[b*HH + t] = geluf(a);
}

// ---------------- S2: e2 | gip | W2 | bvWo | gh0 ----------------
__global__ __launch_bounds__(256) void k_s2(MegaP P){
  __shared__ SMem sm;
  const int blk = blockIdx.x, t = threadIdx.x;
  if (blk < 256){
    const int b = t>>3, cq = t&7;
    const int col = blk*32 + cq*4;
    float4 acc = *(const float4*)(P.b_e2 + col);
    const float* e1b = P.e1 + b*HH;
    const float* w = P.W_e2 + col;
    #pragma unroll 4
    for (int k=0;k<HH;++k){
      float ev = e1b[k];
      float4 wv = *(const float4*)(w + (size_t)k*RD);
      acc.x += ev*wv.x; acc.y += ev*wv.y; acc.z += ev*wv.z; acc.w += ev*wv.w;
    }
    *(float4*)(P.regs + (size_t)b*RD + col) = acc;
  } else if (blk < 352){
    const int i = blk - 256;
    st_mm2(sm, P.pooled, DD, P.W_ih, 0, G3, P.gip_part, i%12, i/12, 1, t);
  } else if (blk < 608){
    st_w2(sm, P, blk-352, t);
  } else if (blk < 612){
    const int col = (blk-608)*256 + t;
    float a = 0.f;
    #pragma unroll 8
    for (int j=0;j<DD;++j) a += P.bv[j]*P.Wo[(size_t)j*DD + col];
    P.bvWo[col] = a;
  } else {
    const int col = (blk-612)*256 + t;
    float a = 0.f;
    #pragma unroll 8
    for (int k=0;k<HH;++k) a += P.h0[k]*P.W_hh[(size_t)k*G3 + col];
    #pragma unroll
    for (int b=0;b<BB;++b) P.ghpart[b*G3 + col] = a;
  }
}

// ---------------- per-step: gi partials with fused deltas (384 x 128t) ----------------
__global__ __launch_bounds__(128) void k_gic(MegaP P, int s){
  __shared__ SMem sm;
  const int nb = blockIdx.x%12, layer = blockIdx.x/12;
  st_mm_regs(sm, P, s, P.W_ih, DD, G3, P.gi_part, nb, layer, threadIdx.x,
             (nb==0 && layer<4));
}

// ---------------- per-step control (32 x 256t): GRU + softmaxes + stats ----------------
__global__ __launch_bounds__(256) void k_control(MegaP P, int s){
  __shared__ SMem sm;
  const int b = blockIdx.x, t = threadIdx.x;
  if (t < 32){
    int sp = t>>3, r = t&7;
    sm.ctl.dws[t] = (sp < s) ? P.dwbuf[(size_t)sp*256 + b*8 + r] : 0.f;
  }
  const float hold = P.hbuf[b*HH + t];
  float gi[3], gh[3];
  #pragma unroll
  for (int j=0;j<3;++j){
    const int n = t + j*256;
    float a = P.b_ih[n];
    #pragma unroll
    for (int l=0;l<8;++l)  a += P.gip_part[(size_t)(l*BB+b)*G3 + n];
    #pragma unroll 8
    for (int l=0;l<32;++l) a += P.gi_part[(size_t)(l*BB+b)*G3 + n];
    gi[j] = a;
    gh[j] = P.b_hh[n] + P.ghpart[b*G3 + n];
  }
  {
    float r = sigf(gi[0]+gh[0]), z = sigf(gi[1]+gh[1]);
    float nn = tanhf(gi[2] + r*gh[2]);
    float hv = (1.0f - z)*nn + z*hold;
    sm.ctl.hnew[t] = hv;
    P.hbuf[b*HH + t] = hv;
  }
  __syncthreads();
  if (t < 40){
    const float* Wc; float bias; int col, ld;
    if (t < 16){ Wc=P.W_op; col=t; ld=16;
      float uu = P.u[s*BB*16 + b*16 + col];
      bias = P.b_op[col] + (-logf(-logf(uu + 1e-20f) + 1e-20f)); }
    else if (t<24){ Wc=P.W_src; col=t-16; ld=8; bias=P.b_src[col]; }
    else if (t<32){ Wc=P.W_dst; col=t-24; ld=8; bias=P.b_dst[col]; }
    else          { Wc=P.W_aux; col=t-32; ld=8; bias=P.b_aux[col]; }
    float a = bias;
    #pragma unroll 4
    for (int k=0;k<HH;++k) a += sm.ctl.hnew[k]*Wc[k*ld + col];
    sm.ctl.logit[t] = a;
  }
  __syncthreads();
  if (t == 0){
    float m = sm.ctl.logit[0]; int am = 0;
    for (int i=1;i<16;++i){ if (sm.ctl.logit[i] > m){ m = sm.ctl.logit[i]; am = i; } }
    float e[16]; float sum = 0.f;
    for (int i=0;i<16;++i){ e[i] = expf(sm.ctl.logit[i]-m); sum += e[i]; }
    float inv = 1.0f/sum;
    for (int i=0;i<16;++i){ float w = e[i]*inv; sm.ctl.wsm[i] = w; P.opw[b*16+i] = w; }
    float hl = P.halt[b] + sm.ctl.wsm[15];
    P.halt[b] = hl;
    P.live[b] = fmaxf(1.0f - hl, 0.0f);
    P.out[OUT_TR + b*NSTEPS + s] = (float)am;
  } else if (t <= 3){
    int base = 16 + (t-1)*8;
    float m = sm.ctl.logit[base];
    for (int i=1;i<8;++i) m = fmaxf(m, sm.ctl.logit[base+i]);
    float e[8]; float sum=0.f;
    for (int i=0;i<8;++i){ e[i]=expf(sm.ctl.logit[base+i]-m); sum+=e[i]; }
    float inv = 1.0f/sum;
    for (int i=0;i<8;++i){
      float w = e[i]*inv; sm.ctl.wsm[base+i] = w;
      if (t==2) P.dwbuf[(size_t)s*256 + b*8 + i] = w;
    }
  }
  __syncthreads();
  float sx,sy,sz,sw;
  {
    float w4 = sm.ctl.wsm[4], w14 = sm.ctl.wsm[14], w6 = sm.ctl.wsm[6];
    sx=0;sy=0;sz=0;sw=0;
    float dx=0,dy=0,dz=0,dw_=0, axx=0,ayy=0,azz=0,aww=0;
    float4 rlq[3];
    #pragma unroll
    for (int sp=0; sp<3; ++sp){
      if (sp < s) rlq[sp] = *(const float4*)(P.rlbuf + ((size_t)sp*BB + b)*DD + t*4);
      else { rlq[sp].x=0;rlq[sp].y=0;rlq[sp].z=0;rlq[sp].w=0; }
    }
    #pragma unroll
    for (int r=0;r<8;++r){
      float ws = sm.ctl.wsm[16+r], wd = sm.ctl.wsm[24+r], wa = sm.ctl.wsm[32+r];
      float4 rv = *(const float4*)(P.regs + (size_t)b*RD + r*DD + t*4);
      #pragma unroll
      for (int sp=0; sp<3; ++sp){
        if (sp < s){
          float dwv = sm.ctl.dws[sp*8+r];
          rv.x += dwv*rlq[sp].x; rv.y += dwv*rlq[sp].y;
          rv.z += dwv*rlq[sp].z; rv.w += dwv*rlq[sp].w;
        }
      }
      sx += ws*rv.x; sy += ws*rv.y; sz += ws*rv.z; sw += ws*rv.w;
      dx += wd*rv.x; dy += wd*rv.y; dz += wd*rv.z; dw_ += wd*rv.w;
      axx += wa*rv.x; ayy += wa*rv.y; azz += wa*rv.z; aww += wa*rv.w;
    }
    float4 o;
    o.x=sx;o.y=sy;o.z=sz;o.w=sw;       *(float4*)(P.srcv + b*DD + t*4) = o;
    o.x=dx;o.y=dy;o.z=dz;o.w=dw_;      *(float4*)(P.dstv + b*DD + t*4) = o;
    o.x = w4*sx + w14*sx*dx;  o.y = w4*sy + w14*sy*dy;
    o.z = w4*sz + w14*sz*dz;  o.w = w4*sw + w14*sw*dw_;
    *(float4*)(P.tvec + b*DD + t*4) = o;
    o.x=w6*axx;o.y=w6*ayy;o.z=w6*azz;o.w=w6*aww;
    *(float4*)(P.avec + b*DD + t*4) = o;
  }
  // stats of srcv row (mean, rstd) for next step's rl
  {
    float s1 = sx+sy+sz+sw;
    float s2 = sx*sx + sy*sy + sz*sz + sw*sw;
    #pragma unroll
    for (int off=32; off; off>>=1){ s1 += __shfl_xor(s1, off, 64); s2 += __shfl_xor(s2, off, 64); }
    if ((t&63)==0){ sm.ctl.redS[t>>6]=s1; sm.ctl.redQ[t>>6]=s2; }
    __syncthreads();
    if (t==0){
      float S = sm.ctl.redS[0]+sm.ctl.redS[1]+sm.ctl.redS[2]+sm.ctl.redS[3];
      float Q = sm.ctl.redQ[0]+sm.ctl.redQ[1]+sm.ctl.redQ[2]+sm.ctl.redQ[3];
      float mean = S*(1.0f/DD);
      float var = Q*(1.0f/DD) - mean*mean;
      P.statsb[b*2]   = mean;
      P.statsb[b*2+1] = rsqrtf(var + 1e-5f);
    }
  }
}

// ---------------- per-step: proj | attn-via-W2 | gh(s+1) (268 x 128t) ----------------
__global__ __launch_bounds__(128) void k_pv(MegaP P){
  __shared__ SMem sm;
  const int blk = blockIdx.x, t = threadIdx.x;
  if (blk < 128)       st_mm2(sm, P.tvec, DD, P.W_proj, 0, DD, P.p8a, blk>>3, blk&7, 1, t);
  else if (blk < 256){ int r = blk-128; st_mm2(sm, P.avec, DD, P.W2, 0, DD, P.p10, r>>3, r&7, 1, t); }
  else               { int r = blk-256; st_mm2(sm, P.hbuf, HH, P.W_hh, 0, G3, P.ghpart, r, 0, 2, t); }
}

// ---------------- d1 partials with fused deltas + rl[3] persist (128 x 128t) ----------------
__global__ __launch_bounds__(128) void k_d1(MegaP P){
  __shared__ SMem sm;
  const int nb = blockIdx.x & 3, layer = blockIdx.x >> 2;
  st_mm_regs(sm, P, NSTEPS, P.W_d1, 0, HH, P.d1part, nb, layer, threadIdx.x,
             (nb==0 && layer<4));
}

// ---------------- decode (32 x 256t): d2 + rmsnorm + delta-applied regs out ----------------
__global__ __launch_bounds__(256) void k_decode(MegaP P){
  __shared__ SMem sm;
  const int b = blockIdx.x, t = threadIdx.x;
  if (t < 32) sm.dec.dws[t] = P.dwbuf[(size_t)(t>>3)*256 + b*8 + (t&7)];
  float a = P.b_d1[t];
  #pragma unroll 8
  for (int l=0;l<32;++l) a += P.d1part[(size_t)(l*BB+b)*HH + t];
  sm.dec.d1[t] = geluf(a);
  __syncthreads();
  float4 acc = *(const float4*)(P.b_d2 + t*4);
  #pragma unroll 4
  for (int k=0;k<HH;++k){
    float4 w = *(const float4*)(P.W_d2 + (size_t)k*DD + t*4);
    float dk = sm.dec.d1[k];
    acc.x += dk*w.x; acc.y += dk*w.y; acc.z += dk*w.z; acc.w += dk*w.w;
  }
  float q = acc.x*acc.x + acc.y*acc.y + acc.z*acc.z + acc.w*acc.w;
  #pragma unroll
  for (int off=32; off; off>>=1) q += __shfl_xor(q, off, 64);
  if ((t&63)==0) sm.dec.redQ[t>>6]=q;
  __syncthreads();
  if (t==0) sm.dec.stats[0] = rsqrtf((sm.dec.redQ[0]+sm.dec.redQ[1]+sm.dec.redQ[2]+sm.dec.redQ[3])*(1.0f/DD) + 1e-6f);
  __syncthreads();
  const float rs = sm.dec.stats[0];
  float4 nw = *(const float4*)(P.norm_w + t*4);
  float4 po;
  po.x = acc.x*rs*nw.x; po.y = acc.y*rs*nw.y; po.z = acc.z*rs*nw.z; po.w = acc.w*rs*nw.w;
  *(float4*)(P.pn + (size_t)b*DD + t*4) = po;
  *(float4*)(P.out + OUT_PO + (size_t)b*DD + t*4) = po;
  const float4* rsrc = (const float4*)(P.regs + (size_t)b*RD);
  float4* rdst = (float4*)(P.out + OUT_REGS + (size_t)b*RD);
  for (int i=t;i<RD/4;i+=256){
    float4 v = rsrc[i];
    const int r = i >> 8;
    const int dq = (i & 255)*4;
    #pragma unroll
    for (int sp=0; sp<4; ++sp){
      float4 rv = *(const float4*)(P.rlbuf + ((size_t)sp*BB + b)*DD + dq);
      float dwv = sm.dec.dws[sp*8+r];
      v.x += dwv*rv.x; v.y += dwv*rv.y; v.z += dwv*rv.z; v.w += dwv*rv.w;
    }
    rdst[i] = v;
  }
}

// ---------------- x_prog = rmsnorm(x + 0.1*pn, norm_w) ----------------
__global__ __launch_bounds__(256) void k_xprog(
    const float* __restrict__ x, const float* __restrict__ pn,
    const float* __restrict__ norm_w, float* __restrict__ out)
{
  const int t = threadIdx.x;
  const int lane = t & 63;
  const int w = blockIdx.x*4 + (t>>6);
  const int row0 = w*4;
  const int b = row0 >> 11;
  float4 nw[4], pv[4];
  #pragma unroll
  for (int j=0;j<4;++j){
    nw[j] = *(const float4*)(norm_w + j*256 + lane*4);
    float4 p = *(const float4*)(pn + (size_t)b*DD + j*256 + lane*4);
    pv[j].x = 0.1f*p.x; pv[j].y = 0.1f*p.y; pv[j].z = 0.1f*p.z; pv[j].w = 0.1f*p.w;
  }
  #pragma unroll
  for (int r=0;r<4;++r){
    const int row = row0 + r;
    const float* xp = x + (size_t)row*DD;
    float4 y[4]; float ss = 0.f;
    #pragma unroll
    for (int j=0;j<4;++j){
      float4 xv = *(const float4*)(xp + j*256 + lane*4);
      y[j].x = xv.x + pv[j].x; y[j].y = xv.y + pv[j].y;
      y[j].z = xv.z + pv[j].z; y[j].w = xv.w + pv[j].w;
      ss += y[j].x*y[j].x + y[j].y*y[j].y + y[j].z*y[j].z + y[j].w*y[j].w;
    }
    #pragma unroll
    for (int off=32; off; off>>=1) ss += __shfl_xor(ss, off, 64);
    float rsd = rsqrtf(ss*(1.0f/DD) + 1e-6f);
    float* op = out + (size_t)row*DD;
    #pragma unroll
    for (int j=0;j<4;++j){
      float4 o;
      o.x=y[j].x*rsd*nw[j].x; o.y=y[j].y*rsd*nw[j].y;
      o.z=y[j].z*rsd*nw[j].z; o.w=y[j].w*rsd*nw[j].w;
      *(float4*)(op + j*256 + lane*4) = o;
    }
  }
}

extern "C" void kernel_launch(void* const* d_in, const int* in_sizes, int n_in,
                              void* d_out, int out_size, void* d_ws, size_t ws_size,
                              hipStream_t stream)
{
  (void)in_sizes; (void)n_in; (void)out_size; (void)ws_size;
  float* out = (float*)d_out;
  float* ws  = (float*)d_ws;

  size_t o = 0;
  float* pool_part = ws + o; o += 32UL*32*1024;
  float* pooled    = ws + o; o += 32UL*1024;
  float* e1        = ws + o; o += 32UL*256;
  float* regs      = ws + o; o += 32UL*8192;
  float* gip_part  = ws + o; o += 8UL*32*768;
  float* gi_part   = ws + o; o += 32UL*32*768;
  float* ghpart    = ws + o; o += 32UL*768;
  float* hbuf      = ws + o; o += 32UL*256;
  float* halt      = ws + o; o += 32;
  float* opw       = ws + o; o += 32*16;
  float* live      = ws + o; o += 32;
  float* srcv      = ws + o; o += 32UL*1024;
  float* dstv      = ws + o; o += 32UL*1024;
  float* tvec      = ws + o; o += 32UL*1024;
  float* avec      = ws + o; o += 32UL*1024;
  float* p8a       = ws + o; o += 8UL*32*1024;
  float* p10       = ws + o; o += 8UL*32*1024;
  float* d1part    = ws + o; o += 32UL*32*256;
  float* pn        = ws + o; o += 32UL*1024;
  float* W2        = ws + o; o += 1024UL*1024;
  float* bvWo      = ws + o; o += 1024;
  float* rlbuf     = ws + o; o += 4UL*32*1024;
  float* dwbuf     = ws + o; o += 4UL*32*8;
  float* statsb    = ws + o; o += 64;

  MegaP P;
  P.x     = (const float*)d_in[0];
  P.u     = (const float*)d_in[1];
  P.W_e1  = (const float*)d_in[2];
  P.b_e1  = (const float*)d_in[3];
  P.W_e2  = (const float*)d_in[4];
  P.b_e2  = (const float*)d_in[5];
  P.W_ih  = (const float*)d_in[6];
  P.b_ih  = (const float*)d_in[7];
  P.W_hh  = (const float*)d_in[8];
  P.b_hh  = (const float*)d_in[9];
  P.h0    = (const float*)d_in[10];
  P.W_op  = (const float*)d_in[11];
  P.b_op  = (const float*)d_in[12];
  P.W_src = (const float*)d_in[13];
  P.b_src = (const float*)d_in[14];
  P.W_dst = (const float*)d_in[15];
  P.b_dst = (const float*)d_in[16];
  P.W_aux = (const float*)d_in[17];
  P.b_aux = (const float*)d_in[18];
  P.W_proj= (const float*)d_in[19];
  P.op_sc = (const float*)d_in[20];
  P.Wv    = (const float*)d_in[21];
  P.bv    = (const float*)d_in[22];
  P.Wo    = (const float*)d_in[23];
  P.bo    = (const float*)d_in[24];
  P.W_d1  = (const float*)d_in[25];
  P.b_d1  = (const float*)d_in[26];
  P.W_d2  = (const float*)d_in[27];
  P.b_d2  = (const float*)d_in[28];
  P.norm_w= (const float*)d_in[29];
  P.pool_part=pool_part; P.pooled=pooled; P.e1=e1; P.regs=regs;
  P.gip_part=gip_part; P.gi_part=gi_part; P.ghpart=ghpart; P.hbuf=hbuf; P.halt=halt;
  P.opw=opw; P.live=live; P.srcv=srcv; P.dstv=dstv;
  P.tvec=tvec; P.avec=avec; P.p8a=p8a; P.p10=p10; P.d1part=d1part; P.pn=pn;
  P.W2=W2; P.bvWo=bvWo; P.rlbuf=rlbuf; P.dwbuf=dwbuf; P.statsb=statsb; P.out=out;

  hipLaunchKernelGGL(k_pool, dim3(1024), dim3(256), 0, stream, P);
  hipLaunchKernelGGL(k_s1,   dim3(32),   dim3(256), 0, stream, P);
  hipLaunchKernelGGL(k_s2,   dim3(615),  dim3(256), 0, stream, P);
  for (int s=0;s<NSTEPS;++s){
    hipLaunchKernelGGL(k_gic,     dim3(384), dim3(128), 0, stream, P, s);
    hipLaunchKernelGGL(k_control, dim3(32),  dim3(256), 0, stream, P, s);
    hipLaunchKernelGGL(k_pv,      dim3(268), dim3(128), 0, stream, P);
  }
  hipLaunchKernelGGL(k_d1,     dim3(128), dim3(128), 0, stream, P);
  hipLaunchKernelGGL(k_decode, dim3(32),  dim3(256), 0, stream, P);
  hipLaunchKernelGGL(k_xprog,  dim3(4096),dim3(256), 0, stream, P.x, pn, P.norm_w, out);
}

// Round 9
// 608.938 us; speedup vs baseline: 1.2977x; 1.2977x over previous
//
#include <hip/hip_runtime.h>
#include <math.h>
#include <stddef.h>

#define BB 32
#define LL 2048
#define DD 1024
#define HH 256
#define NSTEPS 4
#define RD 8192
#define G3 768

#define OUT_REGS 67108864UL
#define OUT_PO   67371008UL
#define OUT_TR   67403776UL

#define MM_KC 128
#define ATS 516  // per-bq stride: 128*4 + 4

__device__ __forceinline__ float sigf(float x){ return 1.0f/(1.0f+expf(-x)); }
__device__ __forceinline__ float geluf(float x){ return x*0.5f*(1.0f+erff(x*0.70710678118654752f)); }

union SMem {
  struct { float At[8*ATS]; float Wt[MM_KC*64]; } mm;                      // 49280 B
  struct { float A[64*68]; float B[64*64]; } w2;
  struct { float hnew[HH]; float logit[40]; float wsm[40]; } ctl;
  struct { float ow[16]; float dw[8]; float redS[4]; float redQ[4]; float stats[2]; } comb;
  struct { float d1[HH]; float redQ[4]; float stats[1]; } dec;
};

struct MegaP {
  const float *x, *u, *W_e1, *b_e1, *W_e2, *b_e2, *W_ih, *b_ih, *W_hh, *b_hh, *h0;
  const float *W_op, *b_op, *W_src, *b_src, *W_dst, *b_dst, *W_aux, *b_aux;
  const float *W_proj, *op_sc, *Wv, *bv, *Wo, *bo, *W_d1, *b_d1, *W_d2, *b_d2, *norm_w;
  float *pool_part, *pooled, *e1, *regs, *gip_part, *gi_part, *ghpart, *hbuf, *halt;
  float *opw, *dstw, *live, *srcv, *dstv, *tvec, *avec, *p8a, *p10, *d1part, *pn;
  float *W2, *bvWo;
  float *out;
};

// ---------------- generic tiled partial matmul with nk-chunk K accumulation ----------------
__device__ void st_mm2(SMem& sm, const float* __restrict__ in, int in_ld,
                       const float* __restrict__ W, int row_off, int ldw,
                       float* __restrict__ part, int nb, int layer, int nk, int t){
  float acc[16];
  #pragma unroll
  for (int i=0;i<16;++i) acc[i]=0.f;
  const int n0 = nb*64;
  for (int c=0;c<nk;++c){
    const int k0 = (layer*nk + c)*MM_KC;
    __syncthreads();
    if (t < 128){
      #pragma unroll
      for (int rep=0; rep<8; ++rep){
        int idx = t + rep*128;
        int b = idx & 31, k4 = idx >> 5;
        float4 g = *(const float4*)(in + (size_t)b*in_ld + k0 + k4*4);
        float* a = sm.mm.At + (b>>2)*ATS + k4*16 + (b&3);
        a[0]=g.x; a[4]=g.y; a[8]=g.z; a[12]=g.w;
      }
      #pragma unroll
      for (int rep=0; rep<16; ++rep){
        int idx = t + rep*128;
        int k = idx >> 4, nq4 = idx & 15;
        *(float4*)(sm.mm.Wt + k*64 + nq4*4) =
          *(const float4*)(W + (size_t)(row_off + k0 + k)*ldw + n0 + nq4*4);
      }
    }
    __syncthreads();
    if (t < 128){
      const int nq = t & 15, bq = t >> 4;
      const float4* A4 = (const float4*)sm.mm.At + bq*129;
      const float4* W4 = (const float4*)sm.mm.Wt + nq;
      #pragma unroll 4
      for (int kk=0; kk<MM_KC; ++kk){
        float4 a = A4[kk];
        float4 w = W4[kk*16];
        acc[0] +=a.x*w.x; acc[1] +=a.x*w.y; acc[2] +=a.x*w.z; acc[3] +=a.x*w.w;
        acc[4] +=a.y*w.x; acc[5] +=a.y*w.y; acc[6] +=a.y*w.z; acc[7] +=a.y*w.w;
        acc[8] +=a.z*w.x; acc[9] +=a.z*w.y; acc[10]+=a.z*w.z; acc[11]+=a.z*w.w;
        acc[12]+=a.w*w.x; acc[13]+=a.w*w.y; acc[14]+=a.w*w.z; acc[15]+=a.w*w.w;
      }
    }
  }
  if (t < 128){
    const int nq = t & 15, bq = t >> 4;
    float* pp = part + (size_t)(layer*32 + bq*4)*ldw + n0 + nq*4;
    #pragma unroll
    for (int i=0;i<4;++i){
      float4 o; o.x=acc[i*4]; o.y=acc[i*4+1]; o.z=acc[i*4+2]; o.w=acc[i*4+3];
      *(float4*)(pp + (size_t)i*ldw) = o;
    }
  }
}

// ---------------- W2 = Wv @ Wo (one 64x64 tile per virtual block 0-255) ----------------
__device__ void st_w2(SMem& sm, const MegaP& P, int blk, int t){
  const int r0 = (blk>>4)*64, n0 = (blk&15)*64;
  const int tr = t>>4, tc = t&15;
  float4 acc[4];
  acc[0]=make_float4(0,0,0,0); acc[1]=make_float4(0,0,0,0);
  acc[2]=make_float4(0,0,0,0); acc[3]=make_float4(0,0,0,0);
  for (int kc=0; kc<16; ++kc){
    const int k0 = kc*64;
    __syncthreads();
    #pragma unroll
    for (int rep=0; rep<4; ++rep){
      int idx = t + rep*256;
      int r = idx>>4, c4 = (idx&15)*4;
      *(float4*)(sm.w2.A + r*68 + c4) = *(const float4*)(P.Wv + (size_t)(r0+r)*DD + k0 + c4);
      *(float4*)(sm.w2.B + r*64 + c4) = *(const float4*)(P.Wo + (size_t)(k0+r)*DD + n0 + c4);
    }
    __syncthreads();
    #pragma unroll 4
    for (int k=0;k<64;++k){
      float4 bv4 = *(const float4*)(sm.w2.B + k*64 + tc*4);
      float a0 = sm.w2.A[(tr*4+0)*68 + k];
      float a1 = sm.w2.A[(tr*4+1)*68 + k];
      float a2 = sm.w2.A[(tr*4+2)*68 + k];
      float a3 = sm.w2.A[(tr*4+3)*68 + k];
      acc[0].x += a0*bv4.x; acc[0].y += a0*bv4.y; acc[0].z += a0*bv4.z; acc[0].w += a0*bv4.w;
      acc[1].x += a1*bv4.x; acc[1].y += a1*bv4.y; acc[1].z += a1*bv4.z; acc[1].w += a1*bv4.w;
      acc[2].x += a2*bv4.x; acc[2].y += a2*bv4.y; acc[2].z += a2*bv4.z; acc[2].w += a2*bv4.w;
      acc[3].x += a3*bv4.x; acc[3].y += a3*bv4.y; acc[3].z += a3*bv4.z; acc[3].w += a3*bv4.w;
    }
  }
  #pragma unroll
  for (int i=0;i<4;++i)
    *(float4*)(P.W2 + (size_t)(r0+tr*4+i)*DD + n0 + tc*4) = acc[i];
}

// ---------------- pool partials ONLY (no LDS -> max occupancy, pure HBM stream) ----------------
__global__ __launch_bounds__(256) void k_pool(MegaP P){
  const int blk = blockIdx.x, t = threadIdx.x;
  const int b = blk >> 5, c = blk & 31;
  const float* xp = P.x + (size_t)b*LL*DD + (size_t)c*64*DD + t*4;
  float ax=0.f, ay=0.f, az=0.f, aw=0.f;
  #pragma unroll 8
  for (int l=0;l<64;++l){
    float4 v = *(const float4*)(xp + (size_t)l*DD);
    ax+=v.x; ay+=v.y; az+=v.z; aw+=v.w;
  }
  float4 o; o.x=ax; o.y=ay; o.z=az; o.w=aw;
  *(float4*)(P.pool_part + (size_t)blk*DD + t*4) = o;
}

// ---------------- S1: pool finalize + h/halt init + e1 (32) | bvWo (4) | gh0 (3) ----------------
__global__ __launch_bounds__(256) void k_s1(MegaP P){
  __shared__ float pbuf[DD];
  const int blk = blockIdx.x, t = threadIdx.x;
  if (blk < 32){
    const int b = blk;
    float ax=0.f, ay=0.f, az=0.f, aw=0.f;
    #pragma unroll 8
    for (int c=0;c<32;++c){
      float4 v = *(const float4*)(P.pool_part + (size_t)(b*32+c)*DD + t*4);
      ax+=v.x; ay+=v.y; az+=v.z; aw+=v.w;
    }
    const float inv = 1.0f/(float)LL;
    float4 o; o.x=ax*inv; o.y=ay*inv; o.z=az*inv; o.w=aw*inv;
    *(float4*)(P.pooled + (size_t)b*DD + t*4) = o;
    *(float4*)(pbuf + t*4) = o;
    P.hbuf[b*HH + t] = P.h0[t];
    if (t==0) P.halt[b] = 0.f;
    __syncthreads();
    float a0=0.f,a1=0.f,a2=0.f,a3=0.f;
    #pragma unroll 2
    for (int k=0;k<DD;k+=4){
      a0 += pbuf[k]  *P.W_e1[(k)*HH + t];
      a1 += pbuf[k+1]*P.W_e1[(k+1)*HH + t];
      a2 += pbuf[k+2]*P.W_e1[(k+2)*HH + t];
      a3 += pbuf[k+3]*P.W_e1[(k+3)*HH + t];
    }
    float a = (a0+a1)+(a2+a3) + P.b_e1[t];
    P.e1[b*HH + t] = geluf(a);
  } else if (blk < 36){
    const int col = (blk-32)*256 + t;
    float a = 0.f;
    #pragma unroll 8
    for (int j=0;j<DD;++j) a += P.bv[j]*P.Wo[(size_t)j*DD + col];
    P.bvWo[col] = a;
  } else {
    const int col = (blk-36)*256 + t;     // gh0 = h0 @ W_hh -> layer0; zero layer1
    float a = 0.f;
    #pragma unroll 8
    for (int k=0;k<HH;++k) a += P.h0[k]*P.W_hh[(size_t)k*G3 + col];
    #pragma unroll
    for (int b=0;b<BB;++b){
      P.ghpart[(size_t)b*G3 + col] = a;
      P.ghpart[(size_t)(32+b)*G3 + col] = 0.f;
    }
  }
}

// ---------------- S2: e2 (256) | gip (96) | W2 (256)  -> 608 blocks ----------------
__global__ __launch_bounds__(256) void k_s2(MegaP P){
  __shared__ SMem sm;
  const int blk = blockIdx.x, t = threadIdx.x;
  if (blk < 256){
    const int b = t>>3, cq = t&7;
    const int col = blk*32 + cq*4;
    float4 acc = *(const float4*)(P.b_e2 + col);
    const float* e1b = P.e1 + b*HH;
    const float* w = P.W_e2 + col;
    #pragma unroll 4
    for (int k=0;k<HH;++k){
      float ev = e1b[k];
      float4 wv = *(const float4*)(w + (size_t)k*RD);
      acc.x += ev*wv.x; acc.y += ev*wv.y; acc.z += ev*wv.z; acc.w += ev*wv.w;
    }
    *(float4*)(P.regs + (size_t)b*RD + col) = acc;
  } else if (blk < 352){
    const int i = blk - 256;               // 96: 12 ntiles x 8 layers
    st_mm2(sm, P.pooled, DD, P.W_ih, 0, G3, P.gip_part, i%12, i/12, 1, t);
  } else {
    st_w2(sm, P, blk-352, t);
  }
}

// ---------------- per-step: gi partials (384 blocks x 128t) ----------------
__global__ __launch_bounds__(128) void k_gi(MegaP P){
  __shared__ SMem sm;
  st_mm2(sm, P.regs, RD, P.W_ih, DD, G3, P.gi_part, blockIdx.x%12, blockIdx.x/12, 2, threadIdx.x);
}

// ---------------- per-step control (32 blocks x 256t) ----------------
__global__ __launch_bounds__(256) void k_control(MegaP P, int s){
  __shared__ SMem sm;
  const int b = blockIdx.x, t = threadIdx.x;
  const float hold = P.hbuf[b*HH + t];
  float gi[3], gh[3];
  #pragma unroll
  for (int j=0;j<3;++j){
    const int n = t + j*256;
    float a = P.b_ih[n];
    #pragma unroll
    for (int l=0;l<8;++l)  a += P.gip_part[(size_t)(l*BB+b)*G3 + n];
    #pragma unroll 8
    for (int l=0;l<32;++l) a += P.gi_part[(size_t)(l*BB+b)*G3 + n];
    gi[j] = a;
    gh[j] = P.b_hh[n] + P.ghpart[(size_t)b*G3 + n] + P.ghpart[(size_t)(32+b)*G3 + n];
  }
  {
    float r = sigf(gi[0]+gh[0]), z = sigf(gi[1]+gh[1]);
    float nn = tanhf(gi[2] + r*gh[2]);
    float hv = (1.0f - z)*nn + z*hold;
    sm.ctl.hnew[t] = hv;
    P.hbuf[b*HH + t] = hv;
  }
  __syncthreads();
  if (t < 40){
    const float* Wc; float bias; int col, ld;
    if (t < 16){ Wc=P.W_op; col=t; ld=16;
      float uu = P.u[s*BB*16 + b*16 + col];
      bias = P.b_op[col] + (-logf(-logf(uu + 1e-20f) + 1e-20f)); }
    else if (t<24){ Wc=P.W_src; col=t-16; ld=8; bias=P.b_src[col]; }
    else if (t<32){ Wc=P.W_dst; col=t-24; ld=8; bias=P.b_dst[col]; }
    else          { Wc=P.W_aux; col=t-32; ld=8; bias=P.b_aux[col]; }
    float a = bias;
    #pragma unroll 4
    for (int k=0;k<HH;++k) a += sm.ctl.hnew[k]*Wc[k*ld + col];
    sm.ctl.logit[t] = a;
  }
  __syncthreads();
  if (t == 0){
    float m = sm.ctl.logit[0]; int am = 0;
    for (int i=1;i<16;++i){ if (sm.ctl.logit[i] > m){ m = sm.ctl.logit[i]; am = i; } }
    float e[16]; float sum = 0.f;
    for (int i=0;i<16;++i){ e[i] = expf(sm.ctl.logit[i]-m); sum += e[i]; }
    float inv = 1.0f/sum;
    for (int i=0;i<16;++i){ float w = e[i]*inv; sm.ctl.wsm[i] = w; P.opw[b*16+i] = w; }
    float hl = P.halt[b] + sm.ctl.wsm[15];
    P.halt[b] = hl;
    P.live[b] = fmaxf(1.0f - hl, 0.0f);
    P.out[OUT_TR + b*NSTEPS + s] = (float)am;
  } else if (t <= 3){
    int base = 16 + (t-1)*8;
    float m = sm.ctl.logit[base];
    for (int i=1;i<8;++i) m = fmaxf(m, sm.ctl.logit[base+i]);
    float e[8]; float sum=0.f;
    for (int i=0;i<8;++i){ e[i]=expf(sm.ctl.logit[base+i]-m); sum+=e[i]; }
    float inv = 1.0f/sum;
    for (int i=0;i<8;++i){
      float w = e[i]*inv; sm.ctl.wsm[base+i] = w;
      if (t==2) P.dstw[b*8+i] = w;
    }
  }
  __syncthreads();
  {
    float w4 = sm.ctl.wsm[4], w14 = sm.ctl.wsm[14], w6 = sm.ctl.wsm[6];
    float sx=0,sy=0,sz=0,sw=0, dx=0,dy=0,dz=0,dw_=0, axx=0,ayy=0,azz=0,aww=0;
    #pragma unroll
    for (int r=0;r<8;++r){
      float ws = sm.ctl.wsm[16+r], wd = sm.ctl.wsm[24+r], wa = sm.ctl.wsm[32+r];
      float4 rv = *(const float4*)(P.regs + (size_t)b*RD + r*DD + t*4);
      sx += ws*rv.x; sy += ws*rv.y; sz += ws*rv.z; sw += ws*rv.w;
      dx += wd*rv.x; dy += wd*rv.y; dz += wd*rv.z; dw_ += wd*rv.w;
      axx += wa*rv.x; ayy += wa*rv.y; azz += wa*rv.z; aww += wa*rv.w;
    }
    float4 o;
    o.x=sx;o.y=sy;o.z=sz;o.w=sw;       *(float4*)(P.srcv + b*DD + t*4) = o;
    o.x=dx;o.y=dy;o.z=dz;o.w=dw_;      *(float4*)(P.dstv + b*DD + t*4) = o;
    o.x = w4*sx + w14*sx*dx;  o.y = w4*sy + w14*sy*dy;
    o.z = w4*sz + w14*sz*dz;  o.w = w4*sw + w14*sw*dw_;
    *(float4*)(P.tvec + b*DD + t*4) = o;
    o.x=w6*axx;o.y=w6*ayy;o.z=w6*azz;o.w=w6*aww;
    *(float4*)(P.avec + b*DD + t*4) = o;
  }
}

// ---------------- per-step: proj (128) | attn-via-W2 (128) | gh(s+1) (24)  -> 280 x 128t ----------------
__global__ __launch_bounds__(128) void k_pv(MegaP P){
  __shared__ SMem sm;
  const int blk = blockIdx.x, t = threadIdx.x;
  if (blk < 128)       st_mm2(sm, P.tvec, DD, P.W_proj, 0, DD, P.p8a, blk>>3, blk&7, 1, t);
  else if (blk < 256){ int r = blk-128; st_mm2(sm, P.avec, DD, P.W2, 0, DD, P.p10, r>>3, r&7, 1, t); }
  else               { int r = blk-256; st_mm2(sm, P.hbuf, HH, P.W_hh, 0, G3, P.ghpart, r%12, r/12, 1, t); }
}

// ---------------- per-step combine (32 blocks) ----------------
__global__ __launch_bounds__(256) void k_combine(MegaP P){
  __shared__ SMem sm;
  const int b = blockIdx.x, t = threadIdx.x;
  if (t<16) sm.comb.ow[t] = P.opw[b*16+t];
  if (t<8)  sm.comb.dw[t] = P.dstw[b*8+t];
  float4 sv = *(const float4*)(P.srcv + b*DD + t*4);
  float4 dv = *(const float4*)(P.dstv + b*DD + t*4);
  float s1 = sv.x+sv.y+sv.z+sv.w;
  float s2 = sv.x*sv.x + sv.y*sv.y + sv.z*sv.z + sv.w*sv.w;
  #pragma unroll
  for (int off=32; off; off>>=1){ s1 += __shfl_xor(s1, off, 64); s2 += __shfl_xor(s2, off, 64); }
  if ((t&63)==0){ sm.comb.redS[t>>6]=s1; sm.comb.redQ[t>>6]=s2; }
  __syncthreads();
  if (t==0){
    float S = sm.comb.redS[0]+sm.comb.redS[1]+sm.comb.redS[2]+sm.comb.redS[3];
    float Q = sm.comb.redQ[0]+sm.comb.redQ[1]+sm.comb.redQ[2]+sm.comb.redQ[3];
    float mean = S*(1.0f/DD);
    float var = Q*(1.0f/DD) - mean*mean;
    sm.comb.stats[0]=mean; sm.comb.stats[1]=rsqrtf(var + 1e-5f);
  }
  __syncthreads();
  const float mean = sm.comb.stats[0], rstd = sm.comb.stats[1];
  const float live = P.live[b], osc = P.op_sc[0];
  float pmx=0,pmy=0,pmz=0,pmw=0, atx=0,aty=0,atz=0,atw=0;
  #pragma unroll
  for (int l=0;l<8;++l){
    float4 v = *(const float4*)(P.p8a + (size_t)(l*BB+b)*DD + t*4);
    pmx+=v.x; pmy+=v.y; pmz+=v.z; pmw+=v.w;
    float4 w = *(const float4*)(P.p10 + (size_t)(l*BB+b)*DD + t*4);
    atx+=w.x; aty+=w.y; atz+=w.z; atw+=w.w;
  }
  float4 bo4 = *(const float4*)(P.bo + t*4);
  float4 bw4 = *(const float4*)(P.bvWo + t*4);
  atx += sm.comb.ow[6]*(bo4.x + bw4.x); aty += sm.comb.ow[6]*(bo4.y + bw4.y);
  atz += sm.comb.ow[6]*(bo4.z + bw4.z); atw += sm.comb.ow[6]*(bo4.w + bw4.w);
  float S[4]={sv.x,sv.y,sv.z,sv.w}, Dv[4]={dv.x,dv.y,dv.z,dv.w};
  float PM[4]={pmx,pmy,pmz,pmw}, AT[4]={atx,aty,atz,atw};
  float rl[4];
  #pragma unroll
  for (int c=0;c<4;++c){
    float sc=S[c], dc=Dv[c];
    float r = sm.comb.ow[0]*dc + sm.comb.ow[1]*(dc+sc) + sm.comb.ow[2]*(sigf(sc)*dc)
            + sm.comb.ow[3]*((sc-mean)*rstd)
            + PM[c] + sm.comb.ow[5]*(sc+dc) + AT[c]
            - sm.comb.ow[7]*sc + sm.comb.ow[8]*(sc*osc) + sm.comb.ow[9]*sc
            + sm.comb.ow[10]*fmaxf(sc,dc) + sm.comb.ow[11]*fminf(sc,dc)
            + sm.comb.ow[12]*fmaxf(sc,0.0f)
            + sm.comb.ow[13]*tanhf(sc) + sm.comb.ow[15]*dc;
    rl[c] = r*live;
  }
  #pragma unroll
  for (int r=0;r<8;++r){
    float4* rp = (float4*)(P.regs + (size_t)b*RD + r*DD + t*4);
    float4 rv = *rp;
    rv.x += sm.comb.dw[r]*rl[0]; rv.y += sm.comb.dw[r]*rl[1];
    rv.z += sm.comb.dw[r]*rl[2]; rv.w += sm.comb.dw[r]*rl[3];
    *rp = rv;
  }
}

// ---------------- d1 partials (128 blocks x 128t) ----------------
__global__ __launch_bounds__(128) void k_d1(MegaP P){
  __shared__ SMem sm;
  st_mm2(sm, P.regs, RD, P.W_d1, 0, HH, P.d1part, blockIdx.x&3, blockIdx.x>>2, 2, threadIdx.x);
}

// ---------------- decode (32 blocks) ----------------
__global__ __launch_bounds__(256) void k_decode(MegaP P){
  __shared__ SMem sm;
  const int b = blockIdx.x, t = threadIdx.x;
  float a = P.b_d1[t];
  #pragma unroll 8
  for (int l=0;l<32;++l) a += P.d1part[(size_t)(l*BB+b)*HH + t];
  sm.dec.d1[t] = geluf(a);
  __syncthreads();
  float4 acc = *(const float4*)(P.b_d2 + t*4);
  #pragma unroll 4
  for (int k=0;k<HH;++k){
    float4 w = *(const float4*)(P.W_d2 + (size_t)k*DD + t*4);
    float dk = sm.dec.d1[k];
    acc.x += dk*w.x; acc.y += dk*w.y; acc.z += dk*w.z; acc.w += dk*w.w;
  }
  float q = acc.x*acc.x + acc.y*acc.y + acc.z*acc.z + acc.w*acc.w;
  #pragma unroll
  for (int off=32; off; off>>=1) q += __shfl_xor(q, off, 64);
  if ((t&63)==0) sm.dec.redQ[t>>6]=q;
  __syncthreads();
  if (t==0) sm.dec.stats[0] = rsqrtf((sm.dec.redQ[0]+sm.dec.redQ[1]+sm.dec.redQ[2]+sm.dec.redQ[3])*(1.0f/DD) + 1e-6f);
  __syncthreads();
  const float rs = sm.dec.stats[0];
  float4 nw = *(const float4*)(P.norm_w + t*4);
  float4 po;
  po.x = acc.x*rs*nw.x; po.y = acc.y*rs*nw.y; po.z = acc.z*rs*nw.z; po.w = acc.w*rs*nw.w;
  *(float4*)(P.pn + (size_t)b*DD + t*4) = po;
  *(float4*)(P.out + OUT_PO + (size_t)b*DD + t*4) = po;
  const float4* rsrc = (const float4*)(P.regs + (size_t)b*RD);
  float4* rdst = (float4*)(P.out + OUT_REGS + (size_t)b*RD);
  for (int i=t;i<RD/4;i+=256) rdst[i] = rsrc[i];
}

// ---------------- x_prog = rmsnorm(x + 0.1*pn, norm_w) ----------------
__global__ __launch_bounds__(256) void k_xprog(
    const float* __restrict__ x, const float* __restrict__ pn,
    const float* __restrict__ norm_w, float* __restrict__ out)
{
  const int t = threadIdx.x;
  const int lane = t & 63;
  const int w = blockIdx.x*4 + (t>>6);
  const int row0 = w*4;
  const int b = row0 >> 11;
  float4 nw[4], pv[4];
  #pragma unroll
  for (int j=0;j<4;++j){
    nw[j] = *(const float4*)(norm_w + j*256 + lane*4);
    float4 p = *(const float4*)(pn + (size_t)b*DD + j*256 + lane*4);
    pv[j].x = 0.1f*p.x; pv[j].y = 0.1f*p.y; pv[j].z = 0.1f*p.z; pv[j].w = 0.1f*p.w;
  }
  #pragma unroll
  for (int r=0;r<4;++r){
    const int row = row0 + r;
    const float* xp = x + (size_t)row*DD;
    float4 y[4]; float ss = 0.f;
    #pragma unroll
    for (int j=0;j<4;++j){
      float4 xv = *(const float4*)(xp + j*256 + lane*4);
      y[j].x = xv.x + pv[j].x; y[j].y = xv.y + pv[j].y;
      y[j].z = xv.z + pv[j].z; y[j].w = xv.w + pv[j].w;
      ss += y[j].x*y[j].x + y[j].y*y[j].y + y[j].z*y[j].z + y[j].w*y[j].w;
    }
    #pragma unroll
    for (int off=32; off; off>>=1) ss += __shfl_xor(ss, off, 64);
    float rsd = rsqrtf(ss*(1.0f/DD) + 1e-6f);
    float* op = out + (size_t)row*DD;
    #pragma unroll
    for (int j=0;j<4;++j){
      float4 o;
      o.x=y[j].x*rsd*nw[j].x; o.y=y[j].y*rsd*nw[j].y;
      o.z=y[j].z*rsd*nw[j].z; o.w=y[j].w*rsd*nw[j].w;
      *(float4*)(op + j*256 + lane*4) = o;
    }
  }
}

extern "C" void kernel_launch(void* const* d_in, const int* in_sizes, int n_in,
                              void* d_out, int out_size, void* d_ws, size_t ws_size,
                              hipStream_t stream)
{
  (void)in_sizes; (void)n_in; (void)out_size; (void)ws_size;
  float* out = (float*)d_out;
  float* ws  = (float*)d_ws;

  size_t o = 0;
  float* pool_part = ws + o; o += 32UL*32*1024;
  float* pooled    = ws + o; o += 32UL*1024;
  float* e1        = ws + o; o += 32UL*256;
  float* regs      = ws + o; o += 32UL*8192;
  float* gip_part  = ws + o; o += 8UL*32*768;
  float* gi_part   = ws + o; o += 32UL*32*768;
  float* ghpart    = ws + o; o += 2UL*32*768;
  float* hbuf      = ws + o; o += 32UL*256;
  float* halt      = ws + o; o += 32;
  float* opw       = ws + o; o += 32*16;
  float* dstw      = ws + o; o += 32*8;
  float* live      = ws + o; o += 32;
  float* srcv      = ws + o; o += 32UL*1024;
  float* dstv      = ws + o; o += 32UL*1024;
  float* tvec      = ws + o; o += 32UL*1024;
  float* avec      = ws + o; o += 32UL*1024;
  float* p8a       = ws + o; o += 8UL*32*1024;
  float* p10       = ws + o; o += 8UL*32*1024;
  float* d1part    = ws + o; o += 32UL*32*256;
  float* pn        = ws + o; o += 32UL*1024;
  float* W2        = ws + o; o += 1024UL*1024;
  float* bvWo      = ws + o; o += 1024;

  MegaP P;
  P.x     = (const float*)d_in[0];
  P.u     = (const float*)d_in[1];
  P.W_e1  = (const float*)d_in[2];
  P.b_e1  = (const float*)d_in[3];
  P.W_e2  = (const float*)d_in[4];
  P.b_e2  = (const float*)d_in[5];
  P.W_ih  = (const float*)d_in[6];
  P.b_ih  = (const float*)d_in[7];
  P.W_hh  = (const float*)d_in[8];
  P.b_hh  = (const float*)d_in[9];
  P.h0    = (const float*)d_in[10];
  P.W_op  = (const float*)d_in[11];
  P.b_op  = (const float*)d_in[12];
  P.W_src = (const float*)d_in[13];
  P.b_src = (const float*)d_in[14];
  P.W_dst = (const float*)d_in[15];
  P.b_dst = (const float*)d_in[16];
  P.W_aux = (const float*)d_in[17];
  P.b_aux = (const float*)d_in[18];
  P.W_proj= (const float*)d_in[19];
  P.op_sc = (const float*)d_in[20];
  P.Wv    = (const float*)d_in[21];
  P.bv    = (const float*)d_in[22];
  P.Wo    = (const float*)d_in[23];
  P.bo    = (const float*)d_in[24];
  P.W_d1  = (const float*)d_in[25];
  P.b_d1  = (const float*)d_in[26];
  P.W_d2  = (const float*)d_in[27];
  P.b_d2  = (const float*)d_in[28];
  P.norm_w= (const float*)d_in[29];
  P.pool_part=pool_part; P.pooled=pooled; P.e1=e1; P.regs=regs;
  P.gip_part=gip_part; P.gi_part=gi_part; P.ghpart=ghpart; P.hbuf=hbuf; P.halt=halt;
  P.opw=opw; P.dstw=dstw; P.live=live; P.srcv=srcv; P.dstv=dstv;
  P.tvec=tvec; P.avec=avec; P.p8a=p8a; P.p10=p10; P.d1part=d1part; P.pn=pn;
  P.W2=W2; P.bvWo=bvWo; P.out=out;

  hipLaunchKernelGGL(k_pool, dim3(1024), dim3(256), 0, stream, P);
  hipLaunchKernelGGL(k_s1,   dim3(39),   dim3(256), 0, stream, P);
  hipLaunchKernelGGL(k_s2,   dim3(608),  dim3(256), 0, stream, P);
  for (int s=0;s<NSTEPS;++s){
    hipLaunchKernelGGL(k_gi,      dim3(384), dim3(128), 0, stream, P);
    hipLaunchKernelGGL(k_control, dim3(32),  dim3(256), 0, stream, P, s);
    hipLaunchKernelGGL(k_pv,      dim3(280), dim3(128), 0, stream, P);
    hipLaunchKernelGGL(k_combine, dim3(32),  dim3(256), 0, stream, P);
  }
  hipLaunchKernelGGL(k_d1,     dim3(128), dim3(128), 0, stream, P);
  hipLaunchKernelGGL(k_decode, dim3(32),  dim3(256), 0, stream, P);
  hipLaunchKernelGGL(k_xprog,  dim3(4096),dim3(256), 0, stream, P.x, pn, P.norm_w, out);
}